// Round 2
// baseline (1623.763 us; speedup 1.0000x reference)
//
#include <hip/hip_runtime.h>

#define BB_ 8
#define NN_ 8192
#define SS_ 2048
#define NS 32
#define C1 64
#define C2 64
#define C3 128
#define RAD2 0.04f
#define BN_EPS 1e-5f
#define M_TOT (BB_*SS_*NS)   // 524288
#define NTILE (M_TOT/64)     // 8192 tiles of 64 points (= 2 groups)

// ws layout (float offsets)
#define FEAT_OFF 0                 // SoA [6][M_TOT] = 3145728
#define GMM_OFF  3145728           // float2 per (group, o3): 16384*128*2 = 4194304
#define ST_OFF   7340032           // 448: fsum[6] G[21] (pad to 32) | sum2[64] sq2[64] | sum3[128] sq3[128]
#define AFF_OFF  7340480           // 512: a1 c1 a2 c2 (64 ea) | a3 c3 (128 ea)

// ---------------- ball query + feat0 (SoA) + out_xyz ----------------
__global__ void k_ballquery(const float* __restrict__ xyz, const float* __restrict__ pts,
                            const int* __restrict__ fps,
                            float* __restrict__ feat0, float* __restrict__ out_xyz) {
    __shared__ int lidx[4][NS];
    int wave = (blockIdx.x * blockDim.x + threadIdx.x) >> 6;   // one wave per query
    int lane = threadIdx.x & 63;
    int wslot = threadIdx.x >> 6;
    int b = wave / SS_, s = wave - b * SS_;
    const float* xb = xyz + (size_t)b * 3 * NN_;
    const float* pb = pts + (size_t)b * 3 * NN_;
    int ci = fps[wave];
    float cx = xb[ci], cy = xb[NN_ + ci], cz = xb[2 * NN_ + ci];

    int found = 0;
    int first_i = -1;
    for (int base = 0; base < NN_; base += 64) {
        int i = base + lane;
        float dx = xb[i] - cx, dy = xb[NN_ + i] - cy, dz = xb[2 * NN_ + i] - cz;
        float d2 = __fadd_rn(__fadd_rn(__fmul_rn(dx, dx), __fmul_rn(dy, dy)), __fmul_rn(dz, dz));
        bool inr = d2 <= RAD2;
        unsigned long long mask = __ballot(inr);
        if (first_i < 0 && mask) first_i = base + __builtin_ctzll(mask);
        if (inr) {
            int pos = found + __popcll(mask & ((1ull << lane) - 1ull));
            if (pos < NS) lidx[wslot][pos] = i;
        }
        found += __popcll(mask);
        if (found >= NS) break;
    }
    if (found > NS) found = NS;
    __syncthreads();

    if (lane < NS) {
        int j = (lane < found) ? lidx[wslot][lane] : first_i;
        size_t p = (size_t)wave * NS + lane;
        feat0[0 * M_TOT + p] = xb[j] - cx;
        feat0[1 * M_TOT + p] = xb[NN_ + j] - cy;
        feat0[2 * M_TOT + p] = xb[2 * NN_ + j] - cz;
        feat0[3 * M_TOT + p] = pb[j];
        feat0[4 * M_TOT + p] = pb[NN_ + j];
        feat0[5 * M_TOT + p] = pb[2 * NN_ + j];
    }
    if (lane == 0) {
        out_xyz[((size_t)b * 3 + 0) * SS_ + s] = cx;
        out_xyz[((size_t)b * 3 + 1) * SS_ + s] = cy;
        out_xyz[((size_t)b * 3 + 2) * SS_ + s] = cz;
    }
}

// ---------------- P1: f-sums + 6x6 Gram (layer-1 stats via algebra) ----------------
__global__ void k_p1(const float* __restrict__ feat0, float* __restrict__ st) {
    __shared__ float sacc[27];
    int tid = threadIdx.x;
    if (tid < 27) sacc[tid] = 0.f;
    __syncthreads();
    int gt = blockIdx.x * blockDim.x + tid;   // 64*256 = 16384 threads
    float vals[27];
    #pragma unroll
    for (int i = 0; i < 27; ++i) vals[i] = 0.f;
    #pragma unroll 1
    for (int it = 0; it < M_TOT / 16384; ++it) {
        int p = it * 16384 + gt;
        float f[6];
        #pragma unroll
        for (int c = 0; c < 6; ++c) f[c] = feat0[c * M_TOT + p];
        #pragma unroll
        for (int c = 0; c < 6; ++c) vals[c] += f[c];
        int q = 6;
        #pragma unroll
        for (int c = 0; c < 6; ++c)
            #pragma unroll
            for (int d = c; d < 6; ++d) { vals[q] = fmaf(f[c], f[d], vals[q]); ++q; }
    }
    int lane = tid & 63;
    #pragma unroll
    for (int i = 0; i < 27; ++i) {
        float v = vals[i];
        #pragma unroll
        for (int d = 32; d; d >>= 1) v += __shfl_xor(v, d);
        if (lane == 0) atomicAdd(&sacc[i], v);
    }
    __syncthreads();
    if (tid < 27) atomicAdd(&st[tid], sacc[tid]);
}

// ---------------- fin1: layer-1 affine from Gram stats ----------------
__global__ void k_fin1(const float* __restrict__ st, const float* __restrict__ W1,
                       const float* __restrict__ g, const float* __restrict__ bb,
                       float* __restrict__ a, float* __restrict__ c) {
    int o = threadIdx.x;
    if (o >= C1) return;
    float w[6];
    #pragma unroll
    for (int i = 0; i < 6; ++i) w[i] = W1[o * 6 + i];
    float ms = 0.f;
    #pragma unroll
    for (int i = 0; i < 6; ++i) ms = fmaf(w[i], st[i], ms);
    float m = ms / (float)M_TOT;
    float e2 = 0.f;
    #pragma unroll
    for (int ci = 0; ci < 6; ++ci)
        #pragma unroll
        for (int d = 0; d < 6; ++d) {
            int lo = ci < d ? ci : d, hi = ci < d ? d : ci;
            int idx = 6 + lo * 6 - lo * (lo + 1) / 2 + hi;
            e2 = fmaf(w[ci] * w[d], st[idx], e2);
        }
    float var = e2 / (float)M_TOT - m * m;
    float ai = g[o] * (1.0f / sqrtf(var + BN_EPS));
    a[o] = ai;
    c[o] = bb[o] - m * ai;
}

// ---------------- fin: a = g*rsqrt(var+eps), c = b - m*a ----------------
__global__ void k_fin(const float* __restrict__ gsum, const float* __restrict__ gsq,
                      const float* __restrict__ g, const float* __restrict__ bb,
                      float* __restrict__ a, float* __restrict__ c, int C) {
    int t = threadIdx.x;
    if (t < C) {
        float m = gsum[t] / (float)M_TOT;
        float var = gsq[t] / (float)M_TOT - m * m;
        float ai = g[t] * (1.0f / sqrtf(var + BN_EPS));
        a[t] = ai;
        c[t] = bb[t] - m * ai;
    }
}

// ---------------- P2: y1 -> x2 stats (chunked acc, per-wave LDS reduce) ----------------
__global__ __launch_bounds__(256, 4) void k_p2(
        const float* __restrict__ feat0, const float* __restrict__ W1,
        const float* __restrict__ a1, const float* __restrict__ c1,
        const float* __restrict__ W2,
        float* __restrict__ gsum, float* __restrict__ gsq) {
    __shared__ float Xw[4][2][16][68];
    __shared__ float bsum[C2], bsq[C2];
    int tid = threadIdx.x, wid = tid >> 6, lane = tid & 63;
    if (tid < C2) { bsum[tid] = 0.f; bsq[tid] = 0.f; }
    __syncthreads();
    int seg = lane >> 4, cch = lane & 15;
    #pragma unroll 1
    for (int it = 0; it < 4; ++it) {
        int tile = it * 2048 + blockIdx.x * 4 + wid;
        int p = tile * 64 + lane;
        float f[6];
        #pragma unroll
        for (int c = 0; c < 6; ++c) f[c] = feat0[c * M_TOT + p];
        float y1[C1];
        #pragma unroll
        for (int o = 0; o < C1; ++o) {
            float v = 0.f;
            #pragma unroll
            for (int c = 0; c < 6; ++c) v = fmaf(f[c], W1[o * 6 + c], v);
            y1[o] = fmaxf(fmaf(a1[o], v, c1[o]), 0.f);
        }
        #pragma unroll 1
        for (int k = 0; k < 4; ++k) {
            float acc[16];
            #pragma unroll
            for (int cc = 0; cc < 16; ++cc) acc[cc] = 0.f;
            #pragma unroll
            for (int c = 0; c < C1; ++c) {
                float v = y1[c];
                #pragma unroll
                for (int cc = 0; cc < 16; ++cc)
                    acc[cc] = fmaf(v, W2[(k * 16 + cc) * C1 + c], acc[cc]);
            }
            int buf = k & 1;
            #pragma unroll
            for (int cc = 0; cc < 16; ++cc) Xw[wid][buf][cc][lane] = acc[cc];
            __syncthreads();
            const float4* xr = (const float4*)&Xw[wid][buf][cch][seg * 16];
            float s = 0.f, q = 0.f;
            #pragma unroll
            for (int r = 0; r < 4; ++r) {
                float4 v4 = xr[r];
                s += v4.x + v4.y + v4.z + v4.w;
                q = fmaf(v4.x, v4.x, q); q = fmaf(v4.y, v4.y, q);
                q = fmaf(v4.z, v4.z, q); q = fmaf(v4.w, v4.w, q);
            }
            s += __shfl_xor(s, 16); s += __shfl_xor(s, 32);
            q += __shfl_xor(q, 16); q += __shfl_xor(q, 32);
            if (lane < 16) {
                atomicAdd(&bsum[k * 16 + cch], s);
                atomicAdd(&bsq[k * 16 + cch], q);
            }
        }
    }
    __syncthreads();
    if (tid < C2) { atomicAdd(&gsum[tid], bsum[tid]); atomicAdd(&gsq[tid], bsq[tid]); }
}

// ---------------- P3: y1 -> y2 -> x3; stats of x3 + per-group max/min ----------------
__global__ __launch_bounds__(256, 3) void k_p3(
        const float* __restrict__ feat0, const float* __restrict__ W1,
        const float* __restrict__ a1, const float* __restrict__ c1,
        const float* __restrict__ W2, const float* __restrict__ a2, const float* __restrict__ c2,
        const float* __restrict__ W3,
        float* __restrict__ gsum, float* __restrict__ gsq, float2* __restrict__ gmm) {
    __shared__ float Xw[4][2][16][68];
    __shared__ float bsum[C3], bsq[C3];
    int tid = threadIdx.x, wid = tid >> 6, lane = tid & 63;
    if (tid < C3) { bsum[tid] = 0.f; bsq[tid] = 0.f; }
    __syncthreads();
    int seg = lane >> 4, cch = lane & 15;
    #pragma unroll 1
    for (int it = 0; it < 4; ++it) {
        int tile = it * 2048 + blockIdx.x * 4 + wid;
        int p = tile * 64 + lane;
        float f[6];
        #pragma unroll
        for (int c = 0; c < 6; ++c) f[c] = feat0[c * M_TOT + p];
        float y1[C1];
        #pragma unroll
        for (int o = 0; o < C1; ++o) {
            float v = 0.f;
            #pragma unroll
            for (int c = 0; c < 6; ++c) v = fmaf(f[c], W1[o * 6 + c], v);
            y1[o] = fmaxf(fmaf(a1[o], v, c1[o]), 0.f);
        }
        float y2[C2];
        #pragma unroll
        for (int o = 0; o < C2; ++o) {
            float v = 0.f;
            #pragma unroll
            for (int c = 0; c < C1; ++c) v = fmaf(y1[c], W2[o * C1 + c], v);
            y2[o] = fmaxf(fmaf(a2[o], v, c2[o]), 0.f);
        }
        #pragma unroll 1
        for (int k = 0; k < 8; ++k) {
            float acc[16];
            #pragma unroll
            for (int cc = 0; cc < 16; ++cc) acc[cc] = 0.f;
            #pragma unroll
            for (int c = 0; c < C2; ++c) {
                float v = y2[c];
                #pragma unroll
                for (int cc = 0; cc < 16; ++cc)
                    acc[cc] = fmaf(v, W3[(k * 16 + cc) * C2 + c], acc[cc]);
            }
            int buf = k & 1;
            #pragma unroll
            for (int cc = 0; cc < 16; ++cc) Xw[wid][buf][cc][lane] = acc[cc];
            __syncthreads();
            const float4* xr = (const float4*)&Xw[wid][buf][cch][seg * 16];
            float s = 0.f, q = 0.f, mx = -3.4e38f, mn = 3.4e38f;
            #pragma unroll
            for (int r = 0; r < 4; ++r) {
                float4 v4 = xr[r];
                s += v4.x + v4.y + v4.z + v4.w;
                q = fmaf(v4.x, v4.x, q); q = fmaf(v4.y, v4.y, q);
                q = fmaf(v4.z, v4.z, q); q = fmaf(v4.w, v4.w, q);
                mx = fmaxf(mx, fmaxf(fmaxf(v4.x, v4.y), fmaxf(v4.z, v4.w)));
                mn = fminf(mn, fminf(fminf(v4.x, v4.y), fminf(v4.z, v4.w)));
            }
            s += __shfl_xor(s, 16); s += __shfl_xor(s, 32);
            q += __shfl_xor(q, 16); q += __shfl_xor(q, 32);
            mx = fmaxf(mx, __shfl_xor(mx, 16));     // combine seg pairs (0,1) and (2,3)
            mn = fminf(mn, __shfl_xor(mn, 16));
            if (lane < 16) {
                atomicAdd(&bsum[k * 16 + cch], s);
                atomicAdd(&bsq[k * 16 + cch], q);
            }
            if (!(lane & 16)) {                      // lanes 0-15: group A, 32-47: group B
                int g = tile * 2 + (lane >> 5);
                gmm[(size_t)g * C3 + k * 16 + cch] = make_float2(mx, mn);
            }
        }
    }
    __syncthreads();
    if (tid < C3) { atomicAdd(&gsum[tid], bsum[tid]); atomicAdd(&gsq[tid], bsq[tid]); }
}

// ---------------- epilogue: out = relu(a3 * (a3>=0 ? max : min) + c3) ----------------
__global__ void k_out(const float2* __restrict__ gmm, const float* __restrict__ a3,
                      const float* __restrict__ c3, float* __restrict__ outp) {
    int s = blockIdx.x * 256 + threadIdx.x;
    int o = blockIdx.y, b = blockIdx.z;
    float2 mm = gmm[((size_t)(b * SS_ + s)) * C3 + o];
    float a = a3[o], c = c3[o];
    float v = (a >= 0.f) ? mm.x : mm.y;
    outp[((size_t)b * C3 + o) * SS_ + s] = fmaxf(fmaf(a, v, c), 0.f);
}

extern "C" void kernel_launch(void* const* d_in, const int* in_sizes, int n_in,
                              void* d_out, int out_size, void* d_ws, size_t ws_size,
                              hipStream_t stream) {
    (void)in_sizes; (void)n_in; (void)out_size; (void)ws_size;
    const float* xyz = (const float*)d_in[0];
    const float* pts = (const float*)d_in[1];
    const int*   fps = (const int*)d_in[2];
    const float* W1 = (const float*)d_in[3];
    const float* g1 = (const float*)d_in[4];
    const float* b1 = (const float*)d_in[5];
    const float* W2 = (const float*)d_in[6];
    const float* g2 = (const float*)d_in[7];
    const float* b2 = (const float*)d_in[8];
    const float* W3 = (const float*)d_in[9];
    const float* g3 = (const float*)d_in[10];
    const float* b3 = (const float*)d_in[11];
    float* out = (float*)d_out;
    float* ws = (float*)d_ws;

    float* feat0 = ws + FEAT_OFF;
    float2* gmm  = (float2*)(ws + GMM_OFF);
    float* st    = ws + ST_OFF;          // [0..26] fsum+gram
    float* sum2 = st + 64,  *sq2 = st + 128;
    float* sum3 = st + 192, *sq3 = st + 320;
    float* af = ws + AFF_OFF;
    float* a1 = af,       *c1 = af + 64;
    float* a2 = af + 128, *c2 = af + 192;
    float* a3 = af + 256, *c3 = af + 384;

    hipMemsetAsync(st, 0, 448 * sizeof(float), stream);
    k_ballquery<<<(BB_ * SS_) / 4, 256, 0, stream>>>(xyz, pts, fps, feat0, out);
    k_p1<<<64, 256, 0, stream>>>(feat0, st);
    k_fin1<<<1, 64, 0, stream>>>(st, W1, g1, b1, a1, c1);
    k_p2<<<512, 256, 0, stream>>>(feat0, W1, a1, c1, W2, sum2, sq2);
    k_fin<<<1, 128, 0, stream>>>(sum2, sq2, g2, b2, a2, c2, C2);
    k_p3<<<512, 256, 0, stream>>>(feat0, W1, a1, c1, W2, a2, c2, W3, sum3, sq3, gmm);
    k_fin<<<1, 128, 0, stream>>>(sum3, sq3, g3, b3, a3, c3, C3);
    k_out<<<dim3(SS_ / 256, C3, BB_), 256, 0, stream>>>(gmm, a3, c3,
                                                        out + (size_t)BB_ * 3 * SS_);
}

// Round 4
// 247.475 us; speedup vs baseline: 6.5613x; 6.5613x over previous
//
#include <hip/hip_runtime.h>
#include <hip/hip_bf16.h>

#define BB_ 8
#define NN_ 8192
#define SS_ 2048
#define NS 32
#define C1 64
#define C2 64
#define C3 128
#define RAD2 0.04f
#define BN_EPS 1e-5f
#define M_TOT (BB_*SS_*NS)   // 524288

typedef __attribute__((ext_vector_type(8))) short bf16x8;   // 8 bf16 = 4 VGPRs (MFMA A/B frag)
typedef __attribute__((ext_vector_type(4))) float f32x4;    // MFMA C/D frag

// ws float offsets
#define FBF_OFF 0          // feat bf16 [M_TOT][8] = 2,097,152 floats (8 MB)
#define WPK_OFF 2097152    // packed weight frags: 1792 uint4 = 7168 floats
#define ST_OFF  2104320    // 512: gram[27] | sum2@64 sq2@128 | sum3@192 sq3@320
#define AFF_OFF 2104832    // 512: a1 c1 a2 c2 (64 ea) a3@256 c3@384
#define GMM_OFF 2105344    // float2 per (group, o3): 16384*128*2 floats -> ends 6,299,648 (25.2 MB)

__device__ inline unsigned pkbf(float a, float b) {
    __hip_bfloat162 h = __float22bfloat162_rn(make_float2(a, b));
    unsigned r; __builtin_memcpy(&r, &h, 4); return r;
}
__device__ inline bf16x8 asfrag(uint4 v) { bf16x8 r; __builtin_memcpy(&r, &v, 16); return r; }
__device__ inline float bflo(unsigned u) { unsigned x = u << 16; float f; __builtin_memcpy(&f, &x, 4); return f; }
__device__ inline float bfhi(unsigned u) { unsigned x = u & 0xffff0000u; float f; __builtin_memcpy(&f, &x, 4); return f; }

// ---------------- zero the stats block (replaces memset-in-graph) ----------------
__global__ void k_zero(float* __restrict__ st) { st[threadIdx.x] = 0.f; }

// ---------------- ball query -> feat bf16 [pt][8] ----------------
__global__ void k_ballquery(const float* __restrict__ xyz, const float* __restrict__ pts,
                            const int* __restrict__ fps, uint4* __restrict__ fbf) {
    __shared__ int lidx[4][NS];
    int wave = (blockIdx.x * blockDim.x + threadIdx.x) >> 6;
    int lane = threadIdx.x & 63;
    int wslot = threadIdx.x >> 6;
    int b = wave / SS_;
    const float* xb = xyz + (size_t)b * 3 * NN_;
    const float* pb = pts + (size_t)b * 3 * NN_;
    int ci = fps[wave];
    float cx = xb[ci], cy = xb[NN_ + ci], cz = xb[2 * NN_ + ci];

    int found = 0;
    int first_i = -1;
    for (int base = 0; base < NN_; base += 64) {
        int i = base + lane;
        float dx = xb[i] - cx, dy = xb[NN_ + i] - cy, dz = xb[2 * NN_ + i] - cz;
        float d2 = __fadd_rn(__fadd_rn(__fmul_rn(dx, dx), __fmul_rn(dy, dy)), __fmul_rn(dz, dz));
        bool inr = d2 <= RAD2;
        unsigned long long mask = __ballot(inr);
        if (first_i < 0 && mask) first_i = base + __builtin_ctzll(mask);
        if (inr) {
            int pos = found + __popcll(mask & ((1ull << lane) - 1ull));
            if (pos < NS) lidx[wslot][pos] = i;
        }
        found += __popcll(mask);
        if (found >= NS) break;
    }
    if (found > NS) found = NS;
    __syncthreads();

    if (lane < NS) {
        int j = (lane < found) ? lidx[wslot][lane] : first_i;
        uint4 o;
        o.x = pkbf(xb[j] - cx,           xb[NN_ + j] - cy);
        o.y = pkbf(xb[2 * NN_ + j] - cz, pb[j]);
        o.z = pkbf(pb[NN_ + j],          pb[2 * NN_ + j]);
        o.w = 0u;
        fbf[(size_t)wave * NS + lane] = o;
    }
}

// ---------------- dedicated, final writer of out_xyz (depends only on d_in) ----------------
__global__ void k_xyz(const float* __restrict__ xyz, const int* __restrict__ fps,
                      float* __restrict__ out_xyz) {
    int t = blockIdx.x * 256 + threadIdx.x;      // [0, B*3*S)
    if (t >= BB_ * 3 * SS_) return;
    int b = t / (3 * SS_);
    int r = (t / SS_) % 3;
    int s = t % SS_;
    int ci = fps[b * SS_ + s];
    out_xyz[t] = xyz[((size_t)b * 3 + r) * NN_ + ci];
}

// ---------------- prepack W1/W2/W3 into MFMA fragment layout (bf16) ----------------
__global__ void k_pack(const float* __restrict__ W1, const float* __restrict__ W2,
                       const float* __restrict__ W3, uint4* __restrict__ wf) {
    int t = blockIdx.x * 256 + threadIdx.x;
    if (t >= 1792) return;
    int l = t & 63, p = l & 15, qd = l >> 4;
    float v[8];
    if (t < 256) {
        int mt = t >> 6;
        #pragma unroll
        for (int j = 0; j < 8; ++j)
            v[j] = (qd == 0 && j < 6) ? W1[(mt * 16 + p) * 6 + j] : 0.f;   // A[m=o1][k=c]
    } else if (t < 768) {
        int fr = (t - 256) >> 6;           // mt2*2+kf
        int mt = fr >> 1, kf = fr & 1;
        #pragma unroll
        for (int j = 0; j < 8; ++j)
            v[j] = W2[(16 * mt + p) * 64 + kf * 32 + qd * 8 + j];          // A[m=o2][k=c]
    } else {
        int fr = (t - 768) >> 6;           // nt*2+kf
        int nt = fr >> 1, kf = fr & 1;
        #pragma unroll
        for (int j = 0; j < 8; ++j)
            v[j] = W3[(nt * 16 + p) * 64 + kf * 32 + qd * 8 + j];          // B[k=c][n=o3]=W3[n][k]
    }
    uint4 o;
    o.x = pkbf(v[0], v[1]); o.y = pkbf(v[2], v[3]);
    o.z = pkbf(v[4], v[5]); o.w = pkbf(v[6], v[7]);
    wf[t] = o;
}

// ---------------- P1: f-sums + 6x6 Gram over bf16 feat ----------------
__global__ void k_p1(const uint4* __restrict__ fbf, float* __restrict__ st) {
    __shared__ float sacc[27];
    int tid = threadIdx.x;
    if (tid < 27) sacc[tid] = 0.f;
    __syncthreads();
    int gt = blockIdx.x * 256 + tid;   // 16384 threads
    float vals[27];
    #pragma unroll
    for (int i = 0; i < 27; ++i) vals[i] = 0.f;
    #pragma unroll 1
    for (int it = 0; it < M_TOT / 16384; ++it) {
        uint4 w = fbf[it * 16384 + gt];
        float f[6] = { bflo(w.x), bfhi(w.x), bflo(w.y), bfhi(w.y), bflo(w.z), bfhi(w.z) };
        #pragma unroll
        for (int c = 0; c < 6; ++c) vals[c] += f[c];
        int q = 6;
        #pragma unroll
        for (int c = 0; c < 6; ++c)
            #pragma unroll
            for (int d = c; d < 6; ++d) { vals[q] = fmaf(f[c], f[d], vals[q]); ++q; }
    }
    int lane = tid & 63;
    #pragma unroll
    for (int i = 0; i < 27; ++i) {
        float v = vals[i];
        #pragma unroll
        for (int d = 32; d; d >>= 1) v += __shfl_xor(v, d);
        if (lane == 0) atomicAdd(&sacc[i], v);
    }
    __syncthreads();
    if (tid < 27) atomicAdd(&st[tid], sacc[tid]);
}

// ---------------- fin1: layer-1 affine from Gram stats ----------------
__global__ void k_fin1(const float* __restrict__ st, const float* __restrict__ W1,
                       const float* __restrict__ g, const float* __restrict__ bb,
                       float* __restrict__ a, float* __restrict__ c) {
    int o = threadIdx.x;
    if (o >= C1) return;
    float w[6];
    #pragma unroll
    for (int i = 0; i < 6; ++i) w[i] = W1[o * 6 + i];
    float ms = 0.f;
    #pragma unroll
    for (int i = 0; i < 6; ++i) ms = fmaf(w[i], st[i], ms);
    float m = ms / (float)M_TOT;
    float e2 = 0.f;
    #pragma unroll
    for (int ci = 0; ci < 6; ++ci)
        #pragma unroll
        for (int d = 0; d < 6; ++d) {
            int lo = ci < d ? ci : d, hi = ci < d ? d : ci;
            int idx = 6 + lo * 6 - lo * (lo + 1) / 2 + hi;
            e2 = fmaf(w[ci] * w[d], st[idx], e2);
        }
    float var = e2 / (float)M_TOT - m * m;
    float ai = g[o] * (1.0f / sqrtf(var + BN_EPS));
    a[o] = ai;
    c[o] = bb[o] - m * ai;
}

// ---------------- fin: a = g*rsqrt(var+eps), c = b - m*a ----------------
__global__ void k_fin(const float* __restrict__ gsum, const float* __restrict__ gsq,
                      const float* __restrict__ g, const float* __restrict__ bb,
                      float* __restrict__ a, float* __restrict__ c, int C) {
    int t = threadIdx.x;
    if (t < C) {
        float m = gsum[t] / (float)M_TOT;
        float var = gsq[t] / (float)M_TOT - m * m;
        float ai = g[t] * (1.0f / sqrtf(var + BN_EPS));
        a[t] = ai;
        c[t] = bb[t] - m * ai;
    }
}

// ---------------- P2: MFMA layers 1-2 (transposed), x2 stats ----------------
__global__ __launch_bounds__(256) void k_p2(
        const uint4* __restrict__ fbf, const uint4* __restrict__ wpk,
        const float* __restrict__ aff,
        float* __restrict__ gsum, float* __restrict__ gsq) {
    __shared__ unsigned yls[4][2560];      // per-wave y1 tile, rows [pt][40 uints]
    __shared__ float bs[C2], bq[C2];
    int tid = threadIdx.x, wslot = tid >> 6, lane = tid & 63;
    int p = lane & 15, qd = lane >> 4;
    if (tid < C2) { bs[tid] = 0.f; bq[tid] = 0.f; }
    __syncthreads();
    const float* a1 = aff, *c1 = aff + 64;
    const uint4* w1f = wpk;
    const uint4* w2f = wpk + 256;
    unsigned* my = yls[wslot];
    float s2[4][4], q2[4][4];
    #pragma unroll
    for (int i = 0; i < 4; ++i)
        #pragma unroll
        for (int r = 0; r < 4; ++r) { s2[i][r] = 0.f; q2[i][r] = 0.f; }

    #pragma unroll 1
    for (int it = 0; it < 4; ++it) {
        int tile = it * 2048 + blockIdx.x * 4 + wslot;
        int base = tile * 64;
        // layer1 B-frags: f^T (k=c zero-padded to 32, n=pt)
        bf16x8 B1[4];
        #pragma unroll
        for (int nt = 0; nt < 4; ++nt) {
            uint4 v = make_uint4(0u, 0u, 0u, 0u);
            if (qd == 0) v = fbf[base + nt * 16 + p];
            B1[nt] = asfrag(v);
        }
        // layer1 MFMA + bn1 -> y1 LDS rows [pt][ch]
        #pragma unroll
        for (int mt = 0; mt < 4; ++mt) {
            bf16x8 A = asfrag(w1f[mt * 64 + lane]);
            float4 av = *(const float4*)(a1 + mt * 16 + qd * 4);
            float4 cv = *(const float4*)(c1 + mt * 16 + qd * 4);
            #pragma unroll
            for (int nt = 0; nt < 4; ++nt) {
                f32x4 acc = {0.f, 0.f, 0.f, 0.f};
                acc = __builtin_amdgcn_mfma_f32_16x16x32_bf16(A, B1[nt], acc, 0, 0, 0);
                float y0 = fmaxf(fmaf(av.x, acc[0], cv.x), 0.f);
                float y1 = fmaxf(fmaf(av.y, acc[1], cv.y), 0.f);
                float y2 = fmaxf(fmaf(av.z, acc[2], cv.z), 0.f);
                float y3 = fmaxf(fmaf(av.w, acc[3], cv.w), 0.f);
                int a = (nt * 16 + p) * 40 + mt * 8 + qd * 2;
                *(uint2*)&my[a] = make_uint2(pkbf(y0, y1), pkbf(y2, y3));
            }
        }
        __syncthreads();   // y1 writes complete before reads
        // layer2 B-frags: y1^T (k=o1, n=pt)
        bf16x8 B2[4][2];
        #pragma unroll
        for (int nt = 0; nt < 4; ++nt)
            #pragma unroll
            for (int kf = 0; kf < 2; ++kf)
                B2[nt][kf] = asfrag(*(const uint4*)&my[(nt * 16 + p) * 40 + kf * 16 + qd * 4]);
        // layer2 MFMA + stats
        #pragma unroll
        for (int mt = 0; mt < 4; ++mt) {
            f32x4 acc[4];
            #pragma unroll
            for (int nt = 0; nt < 4; ++nt) acc[nt] = (f32x4){0.f, 0.f, 0.f, 0.f};
            #pragma unroll
            for (int kf = 0; kf < 2; ++kf) {
                bf16x8 W = asfrag(w2f[(mt * 2 + kf) * 64 + lane]);
                #pragma unroll
                for (int nt = 0; nt < 4; ++nt)
                    acc[nt] = __builtin_amdgcn_mfma_f32_16x16x32_bf16(W, B2[nt][kf], acc[nt], 0, 0, 0);
            }
            #pragma unroll
            for (int r = 0; r < 4; ++r) {
                float v0 = acc[0][r], v1 = acc[1][r], v2 = acc[2][r], v3 = acc[3][r];
                s2[mt][r] += (v0 + v1) + (v2 + v3);
                q2[mt][r] = fmaf(v0, v0, fmaf(v1, v1, fmaf(v2, v2, fmaf(v3, v3, q2[mt][r]))));
            }
        }
        __syncthreads();   // B2 reads complete before next iter's y1 writes
    }
    // reduce across the 16 p-lanes; channel = 16mt + 4qd + r
    #pragma unroll
    for (int mt = 0; mt < 4; ++mt)
        #pragma unroll
        for (int r = 0; r < 4; ++r) {
            float s = s2[mt][r], q = q2[mt][r];
            #pragma unroll
            for (int off = 1; off <= 8; off <<= 1) { s += __shfl_xor(s, off); q += __shfl_xor(q, off); }
            if (p == 0) {
                atomicAdd(&bs[mt * 16 + qd * 4 + r], s);
                atomicAdd(&bq[mt * 16 + qd * 4 + r], q);
            }
        }
    __syncthreads();
    if (tid < C2) { atomicAdd(&gsum[tid], bs[tid]); atomicAdd(&gsq[tid], bq[tid]); }
}

// ---------------- P3: MFMA layers 1-3, x3 stats + per-group max/min ----------------
__global__ __launch_bounds__(256) void k_p3(
        const uint4* __restrict__ fbf, const uint4* __restrict__ wpk,
        const float* __restrict__ aff,
        float* __restrict__ gsum, float* __restrict__ gsq, float2* __restrict__ gmm) {
    __shared__ unsigned yls[4][2560];      // per-wave y1 then y2 tile (phase-separated by barriers)
    __shared__ float bs[C3], bq[C3];
    int tid = threadIdx.x, wslot = tid >> 6, lane = tid & 63;
    int p = lane & 15, qd = lane >> 4;
    if (tid < 128) bs[tid] = 0.f; else bq[tid - 128] = 0.f;
    __syncthreads();
    const float* a1 = aff, *c1 = aff + 64, *a2 = aff + 128, *c2 = aff + 192;
    const uint4* w1f = wpk;
    const uint4* w2f = wpk + 256;
    const uint4* w3f = wpk + 768;
    unsigned* my = yls[wslot];
    // preload W3^T B-frags (64 VGPRs)
    bf16x8 W3f[8][2];
    #pragma unroll
    for (int nt = 0; nt < 8; ++nt)
        #pragma unroll
        for (int kf = 0; kf < 2; ++kf)
            W3f[nt][kf] = asfrag(w3f[(nt * 2 + kf) * 64 + lane]);
    float gs3[8], gq3[8];
    #pragma unroll
    for (int i = 0; i < 8; ++i) { gs3[i] = 0.f; gq3[i] = 0.f; }

    #pragma unroll 1
    for (int it = 0; it < 4; ++it) {
        int tile = it * 2048 + blockIdx.x * 4 + wslot;
        int base = tile * 64;
        // ---- layer1 ----
        bf16x8 B1[4];
        #pragma unroll
        for (int nt = 0; nt < 4; ++nt) {
            uint4 v = make_uint4(0u, 0u, 0u, 0u);
            if (qd == 0) v = fbf[base + nt * 16 + p];
            B1[nt] = asfrag(v);
        }
        #pragma unroll
        for (int mt = 0; mt < 4; ++mt) {
            bf16x8 A = asfrag(w1f[mt * 64 + lane]);
            float4 av = *(const float4*)(a1 + mt * 16 + qd * 4);
            float4 cv = *(const float4*)(c1 + mt * 16 + qd * 4);
            #pragma unroll
            for (int nt = 0; nt < 4; ++nt) {
                f32x4 acc = {0.f, 0.f, 0.f, 0.f};
                acc = __builtin_amdgcn_mfma_f32_16x16x32_bf16(A, B1[nt], acc, 0, 0, 0);
                float y0 = fmaxf(fmaf(av.x, acc[0], cv.x), 0.f);
                float y1 = fmaxf(fmaf(av.y, acc[1], cv.y), 0.f);
                float y2 = fmaxf(fmaf(av.z, acc[2], cv.z), 0.f);
                float y3 = fmaxf(fmaf(av.w, acc[3], cv.w), 0.f);
                int a = (nt * 16 + p) * 40 + mt * 8 + qd * 2;
                *(uint2*)&my[a] = make_uint2(pkbf(y0, y1), pkbf(y2, y3));
            }
        }
        __syncthreads();   // y1 writes -> y1 reads
        // ---- layer2: read y1 frags ----
        bf16x8 B2[4][2];
        #pragma unroll
        for (int nt = 0; nt < 4; ++nt)
            #pragma unroll
            for (int kf = 0; kf < 2; ++kf)
                B2[nt][kf] = asfrag(*(const uint4*)&my[(nt * 16 + p) * 40 + kf * 16 + qd * 4]);
        __syncthreads();   // y1 reads -> y2 overwrites
        #pragma unroll
        for (int mt = 0; mt < 4; ++mt) {
            f32x4 acc[4];
            #pragma unroll
            for (int nt = 0; nt < 4; ++nt) acc[nt] = (f32x4){0.f, 0.f, 0.f, 0.f};
            #pragma unroll
            for (int kf = 0; kf < 2; ++kf) {
                bf16x8 W = asfrag(w2f[(mt * 2 + kf) * 64 + lane]);
                #pragma unroll
                for (int nt = 0; nt < 4; ++nt)
                    acc[nt] = __builtin_amdgcn_mfma_f32_16x16x32_bf16(W, B2[nt][kf], acc[nt], 0, 0, 0);
            }
            float4 av = *(const float4*)(a2 + mt * 16 + qd * 4);
            float4 cv = *(const float4*)(c2 + mt * 16 + qd * 4);
            #pragma unroll
            for (int nt = 0; nt < 4; ++nt) {
                float y0 = fmaxf(fmaf(av.x, acc[nt][0], cv.x), 0.f);
                float y1 = fmaxf(fmaf(av.y, acc[nt][1], cv.y), 0.f);
                float y2 = fmaxf(fmaf(av.z, acc[nt][2], cv.z), 0.f);
                float y3 = fmaxf(fmaf(av.w, acc[nt][3], cv.w), 0.f);
                int a = (nt * 16 + p) * 40 + mt * 8 + qd * 2;
                *(uint2*)&my[a] = make_uint2(pkbf(y0, y1), pkbf(y2, y3));
            }
        }
        __syncthreads();   // y2 writes -> y2 reads
        // ---- layer3 (normal orientation: D rows = points, cols = o3) ----
        float gmx[2][8], gmn[2][8];
        #pragma unroll
        for (int mt = 0; mt < 4; ++mt) {
            bf16x8 A0 = asfrag(*(const uint4*)&my[(mt * 16 + p) * 40 + qd * 4]);
            bf16x8 A1 = asfrag(*(const uint4*)&my[(mt * 16 + p) * 40 + 16 + qd * 4]);
            f32x4 acc[8];
            #pragma unroll
            for (int nt = 0; nt < 8; ++nt) {
                acc[nt] = __builtin_amdgcn_mfma_f32_16x16x32_bf16(A0, W3f[nt][0],
                            (f32x4){0.f, 0.f, 0.f, 0.f}, 0, 0, 0);
                acc[nt] = __builtin_amdgcn_mfma_f32_16x16x32_bf16(A1, W3f[nt][1], acc[nt], 0, 0, 0);
            }
            int gh = mt >> 1;
            #pragma unroll
            for (int nt = 0; nt < 8; ++nt) {
                float v0 = acc[nt][0], v1 = acc[nt][1], v2 = acc[nt][2], v3 = acc[nt][3];
                gs3[nt] += (v0 + v1) + (v2 + v3);
                gq3[nt] = fmaf(v0, v0, fmaf(v1, v1, fmaf(v2, v2, fmaf(v3, v3, gq3[nt]))));
                float mx = fmaxf(fmaxf(v0, v1), fmaxf(v2, v3));
                float mn = fminf(fminf(v0, v1), fminf(v2, v3));
                if ((mt & 1) == 0) { gmx[gh][nt] = mx; gmn[gh][nt] = mn; }
                else { gmx[gh][nt] = fmaxf(gmx[gh][nt], mx); gmn[gh][nt] = fminf(gmn[gh][nt], mn); }
            }
        }
        // group max/min: reduce over qd (lanes differing in bits 4,5), store from lanes 0-15
        #pragma unroll
        for (int grp = 0; grp < 2; ++grp)
            #pragma unroll
            for (int nt = 0; nt < 8; ++nt) {
                float mx = gmx[grp][nt], mn = gmn[grp][nt];
                mx = fmaxf(mx, __shfl_xor(mx, 16)); mx = fmaxf(mx, __shfl_xor(mx, 32));
                mn = fminf(mn, __shfl_xor(mn, 16)); mn = fminf(mn, __shfl_xor(mn, 32));
                if (lane < 16)
                    gmm[(size_t)(tile * 2 + grp) * C3 + nt * 16 + lane] = make_float2(mx, mn);
            }
        __syncthreads();   // y2 reads -> next iter's y1 writes
    }
    // x3 stats: channel = nt*16 + p; reduce over qd
    #pragma unroll
    for (int nt = 0; nt < 8; ++nt) {
        float s = gs3[nt], q = gq3[nt];
        s += __shfl_xor(s, 16); s += __shfl_xor(s, 32);
        q += __shfl_xor(q, 16); q += __shfl_xor(q, 32);
        if (lane < 16) {
            atomicAdd(&bs[nt * 16 + lane], s);
            atomicAdd(&bq[nt * 16 + lane], q);
        }
    }
    __syncthreads();
    if (tid < C3) { atomicAdd(&gsum[tid], bs[tid]); atomicAdd(&gsq[tid], bq[tid]); }
}

// ---------------- epilogue: out = relu(a3 * (a3>=0 ? max : min) + c3) ----------------
__global__ void k_out(const float2* __restrict__ gmm, const float* __restrict__ a3,
                      const float* __restrict__ c3, float* __restrict__ outp) {
    int s = blockIdx.x * 256 + threadIdx.x;
    int o = blockIdx.y, b = blockIdx.z;
    float2 mm = gmm[((size_t)(b * SS_ + s)) * C3 + o];
    float a = a3[o], c = c3[o];
    float v = (a >= 0.f) ? mm.x : mm.y;
    outp[((size_t)b * C3 + o) * SS_ + s] = fmaxf(fmaf(a, v, c), 0.f);
}

extern "C" void kernel_launch(void* const* d_in, const int* in_sizes, int n_in,
                              void* d_out, int out_size, void* d_ws, size_t ws_size,
                              hipStream_t stream) {
    (void)in_sizes; (void)n_in; (void)out_size; (void)ws_size;
    const float* xyz = (const float*)d_in[0];
    const float* pts = (const float*)d_in[1];
    const int*   fps = (const int*)d_in[2];
    const float* W1 = (const float*)d_in[3];
    const float* g1 = (const float*)d_in[4];
    const float* b1 = (const float*)d_in[5];
    const float* W2 = (const float*)d_in[6];
    const float* g2 = (const float*)d_in[7];
    const float* b2 = (const float*)d_in[8];
    const float* W3 = (const float*)d_in[9];
    const float* g3 = (const float*)d_in[10];
    const float* b3 = (const float*)d_in[11];
    float* out = (float*)d_out;
    float* ws = (float*)d_ws;

    uint4* fbf = (uint4*)(ws + FBF_OFF);
    uint4* wpk = (uint4*)(ws + WPK_OFF);
    float* st  = ws + ST_OFF;
    float* sum2 = st + 64,  *sq2 = st + 128;
    float* sum3 = st + 192, *sq3 = st + 320;
    float* af = ws + AFF_OFF;
    float* a1 = af,       *c1 = af + 64;
    float* a2 = af + 128, *c2 = af + 192;
    float* a3 = af + 256, *c3 = af + 384;
    float2* gmm = (float2*)(ws + GMM_OFF);

    k_zero<<<1, 512, 0, stream>>>(st);
    k_pack<<<7, 256, 0, stream>>>(W1, W2, W3, wpk);
    k_ballquery<<<(BB_ * SS_) / 4, 256, 0, stream>>>(xyz, pts, fps, fbf);
    k_p1<<<64, 256, 0, stream>>>(fbf, st);
    k_fin1<<<1, 64, 0, stream>>>(st, W1, g1, b1, a1, c1);
    k_p2<<<512, 256, 0, stream>>>(fbf, wpk, af, sum2, sq2);
    k_fin<<<1, 128, 0, stream>>>(sum2, sq2, g2, b2, a2, c2, C2);
    k_p3<<<512, 256, 0, stream>>>(fbf, wpk, af, sum3, sq3, gmm);
    k_fin<<<1, 128, 0, stream>>>(sum3, sq3, g3, b3, a3, c3, C3);
    k_out<<<dim3(SS_ / 256, C3, BB_), 256, 0, stream>>>(gmm, a3, c3,
                                                        out + (size_t)BB_ * 3 * SS_);
    k_xyz<<<(BB_ * 3 * SS_ + 255) / 256, 256, 0, stream>>>(xyz, fps, out);
}